// Round 17
// baseline (145.127 us; speedup 1.0000x reference)
//
#include <hip/hip_runtime.h>

#define BB 32
#define CC 512
#define COO 512
#define HH 56
#define WW 56
#define HW 3136
#define NPOS 100352      // B*H*W
#define EPSF 1e-5f

typedef unsigned long long u64;
typedef unsigned int u32;
typedef unsigned short u16;
typedef float f32x4 __attribute__((ext_vector_type(4)));
typedef unsigned long long u64x2 __attribute__((ext_vector_type(2)));

// ---------------- workspace layout (bytes) ----------------  total 6,460,928
// s1     : u64[8][NPOS]  = 6,422,528   stage-1 sign bits (word-major)
// wbits  : u64[512*8]    = 32,768      pointwise weight sign bits
// wn     : u64[9*8]      = 576         ~sign(w_dw) per tap per cw
// NT     : u64[3*8*5]    = 960         per-(Nv cat, cw): 4 planes of ~T* + flip
// bn2inv/bn2beta : float[512] each
#define OFF_S1      0
#define OFF_WBITS   6422528
#define OFF_WN      6455296
#define OFF_NT      6455872
#define OFF_BN2INV  6456832
#define OFF_BN2BETA 6458880

__global__ __launch_bounds__(256) void setup_kernel(
    const float* __restrict__ w_dw, const float* __restrict__ w_pw,
    const float* __restrict__ g1, const float* __restrict__ b1,
    const float* __restrict__ m1, const float* __restrict__ v1,
    const float* __restrict__ g2, const float* __restrict__ b2,
    const float* __restrict__ m2, const float* __restrict__ v2,
    u64* __restrict__ wbits, u64* __restrict__ wn, u64* __restrict__ NT,
    float* __restrict__ bn2inv, float* __restrict__ bn2beta) {
    const int t = blockIdx.x * 256 + threadIdx.x;   // 0..4095

    // pointwise weight sign bits (all 4096 threads)
    {
        int o = t >> 3, wi = t & 7;
        const float* wp = w_pw + (size_t)o * CC + wi * 64;
        u64 wrd = 0;
        #pragma unroll 8
        for (int k = 0; k < 64; ++k)
            wrd |= (u64)(wp[k] >= 0.f) << k;
        wbits[t] = wrd;
    }

    if (t < CC) {                       // BN2 affine
        float i2 = g2[t] / sqrtf(v2[t] + EPSF);
        bn2inv[t]  = i2;
        bn2beta[t] = b2[t] - m2[t] * i2;
    } else if (t >= 512 && t < 584) {   // depthwise weight ~sign words
        int q = t - 512, cw = q & 7, tap = q >> 3;   // tap = kh*3+kw
        u64 wv = 0;
        for (int cl = 0; cl < 64; ++cl)
            wv |= (u64)(w_dw[(size_t)(cw * 64 + cl) * 9 + tap] < 0.f) << cl;
        wn[tap * 8 + cw] = wv;
    } else if (t >= 1024 && t < 1048) { // BN1 threshold bitplanes
        int q = t - 1024, cat = q / 8, cw = q % 8;
        const int Nv = (cat == 0) ? 9 : ((cat == 1) ? 6 : 4);
        u64 p0 = 0, p1 = 0, p2 = 0, p3 = 0, F = 0;
        for (int cl = 0; cl < 64; ++cl) {
            int c = cw * 64 + cl;
            float i1 = g1[c] / sqrtf(v1[c] + EPSF);
            float be = b1[c] - m1[c] * i1;
            int T, f;
            if (i1 > 0.f) {
                double h = ((double)Nv - (double)be / (double)i1) * 0.5;
                f = 0;
                if (!(h > 0.0)) T = 0;
                else if (h > 15.0) T = 15;
                else T = (int)ceil(h);
            } else if (i1 < 0.f) {
                double h = ((double)Nv - (double)be / (double)i1) * 0.5;
                f = 1;
                if (h < 0.0) T = 0;
                else if (h >= 15.0) T = 15;
                else { T = (int)floor(h) + 1; if (T > 15) T = 15; }
            } else {
                f = 0;
                T = (be >= 0.f) ? 0 : 15;   // always true / never true (E<=9<15)
            }
            unsigned nt = (~(unsigned)T) & 0xFu;
            p0 |= (u64)(nt & 1) << cl;
            p1 |= (u64)((nt >> 1) & 1) << cl;
            p2 |= (u64)((nt >> 2) & 1) << cl;
            p3 |= (u64)((nt >> 3) & 1) << cl;
            F  |= (u64)f << cl;
        }
        u64* d = NT + (size_t)(cat * 8 + cw) * 5;
        d[0] = p0; d[1] = p1; d[2] = p2; d[3] = p3; d[4] = F;
    }
}

__device__ __forceinline__ void fa(u64 a, u64 b, u64 c, u64& s, u64& cy) {
    u64 ab = a ^ b;
    s  = ab ^ c;
    cy = (ab & c) | (a & b);
}

// Fused: binarize(x) -> LDS bitpack -> depthwise 3x3 + BN1 + sign (bit-domain) -> s1
// [byte-identical to R16 champion: contiguous pack order + NT loads]
__global__ __launch_bounds__(256, 4) void dwfused_kernel(
    const float* __restrict__ x, const u64* __restrict__ wn,
    const u64* __restrict__ NT, u64* __restrict__ s1) {
    __shared__ u64 xb[16 * 56];          // rows r0-1 .. r0+14, 7168 B
    const int strip = blockIdx.x;
    const int cw    = blockIdx.y;
    const int b     = blockIdx.z;
    const int tid   = threadIdx.x;
    const int r0    = strip * 14;

    const float* xc = x + ((size_t)b * CC + cw * 64) * HW;
    u16* xb16 = (u16*)xb;

    // ---- pack phase: 896 tasks = 4 ch-slices x 16 lds-rows x 14 colgroups
    for (int tau = tid; tau < 896; tau += 256) {
        const int cg     = tau / 224;
        const int rem    = tau - cg * 224;
        const int lrow   = rem / 14;
        const int colgrp = rem - lrow * 14;
        const int h      = r0 - 1 + lrow;
        const int col0   = colgrp * 4;
        u16 o0 = 0, o1 = 0, o2 = 0, o3 = 0;
        if (h >= 0 && h < HH) {
            const float* bp = xc + (size_t)(cg * 16) * HW + h * WW + col0;
            f32x4 vv[16];
            #pragma unroll
            for (int cl = 0; cl < 16; ++cl)
                vv[cl] = __builtin_nontemporal_load((const f32x4*)(bp + (size_t)cl * HW));
            u32 a0 = 0, a1 = 0, a2 = 0, a3 = 0;
            #pragma unroll
            for (int cl = 0; cl < 16; ++cl) {
                a0 |= (__float_as_uint(vv[cl].x) >> 31) << cl;
                a1 |= (__float_as_uint(vv[cl].y) >> 31) << cl;
                a2 |= (__float_as_uint(vv[cl].z) >> 31) << cl;
                a3 |= (__float_as_uint(vv[cl].w) >> 31) << cl;
            }
            o0 = (u16)(~a0); o1 = (u16)(~a1); o2 = (u16)(~a2); o3 = (u16)(~a3);
        }
        const int wbase = lrow * 56 + col0;
        xb16[(wbase + 0) * 4 + cg] = o0;
        xb16[(wbase + 1) * 4 + cg] = o1;
        xb16[(wbase + 2) * 4 + cg] = o2;
        xb16[(wbase + 3) * 4 + cg] = o3;
    }
    __syncthreads();

    // ---- compute phase: 196 threads x 4 output words (verified bit logic)
    if (tid >= 196) return;
    const int q      = tid / 14;          // row within strip
    const int colgrp = tid - q * 14;
    const int col0   = colgrp * 4;
    const int r      = r0 + q;            // global row
    const int lrow   = q + 1;

    const int c_m1 = (col0 == 0)  ? 0  : col0 - 1;
    const int c_p4 = (col0 == 52) ? 55 : col0 + 4;

    const u64* rowT = xb + (lrow - 1) * 56;
    const u64* rowM = xb + lrow * 56;
    const u64* rowB = xb + (lrow + 1) * 56;

    u64 rT[6], rM[6], rB[6];
    rT[0] = rowT[c_m1]; rT[1] = rowT[col0];   rT[2] = rowT[col0+1];
    rT[3] = rowT[col0+2]; rT[4] = rowT[col0+3]; rT[5] = rowT[c_p4];
    rM[0] = rowM[c_m1]; rM[1] = rowM[col0];   rM[2] = rowM[col0+1];
    rM[3] = rowM[col0+2]; rM[4] = rowM[col0+3]; rM[5] = rowM[c_p4];
    rB[0] = rowB[c_m1]; rB[1] = rowB[col0];   rB[2] = rowB[col0+1];
    rB[3] = rowB[col0+2]; rB[4] = rowB[col0+3]; rB[5] = rowB[c_p4];

    const u64 w00 = wn[0*8+cw], w01 = wn[1*8+cw], w02 = wn[2*8+cw];
    const u64 w10 = wn[3*8+cw], w11 = wn[4*8+cw], w12 = wn[5*8+cw];
    const u64 w20 = wn[6*8+cw], w21 = wn[7*8+cw], w22 = wn[8*8+cw];

    const u64 mt = (r > 0)    ? ~0ull : 0ull;
    const u64 mb = (r < 55)   ? ~0ull : 0ull;
    const u64 mL = (col0 > 0) ? ~0ull : 0ull;
    const u64 mR = (col0 < 52)? ~0ull : 0ull;

    const bool rowe = (r == 0) || (r == 55);
    const u64* NTc = NT + (size_t)cw * 5;   // cat stride = 40 u64
    u64 A0 = rowe ? NTc[40+0] : NTc[0];
    u64 A1 = rowe ? NTc[40+1] : NTc[1];
    u64 A2 = rowe ? NTc[40+2] : NTc[2];
    u64 A3 = rowe ? NTc[40+3] : NTc[3];
    u64 A4 = rowe ? NTc[40+4] : NTc[4];
    u64 B0 = rowe ? NTc[80+0] : NTc[40+0];
    u64 B1 = rowe ? NTc[80+1] : NTc[40+1];
    u64 B2 = rowe ? NTc[80+2] : NTc[40+2];
    u64 B3 = rowe ? NTc[80+3] : NTc[40+3];
    u64 B4 = rowe ? NTc[80+4] : NTc[40+4];

    u64 out[4];
    #pragma unroll
    for (int j = 0; j < 4; ++j) {
        u64 e0 = (rT[j]   ^ w00) & mt;
        u64 e1 = (rT[j+1] ^ w01) & mt;
        u64 e2 = (rT[j+2] ^ w02) & mt;
        u64 e3 = (rM[j]   ^ w10);
        u64 e4 = (rM[j+1] ^ w11);
        u64 e5 = (rM[j+2] ^ w12);
        u64 e6 = (rB[j]   ^ w20) & mb;
        u64 e7 = (rB[j+1] ^ w21) & mb;
        u64 e8 = (rB[j+2] ^ w22) & mb;
        if (j == 0) { e0 &= mL; e3 &= mL; e6 &= mL; }
        if (j == 3) { e2 &= mR; e5 &= mR; e8 &= mR; }

        u64 sa, ca, sb, cb, sc, cc, E0, cd, se, ce;
        fa(e0, e1, e2, sa, ca);
        fa(e3, e4, e5, sb, cb);
        fa(e6, e7, e8, sc, cc);
        fa(sa, sb, sc, E0, cd);
        fa(ca, cb, cc, se, ce);
        u64 E1 = se ^ cd, cf = se & cd;
        u64 E2 = ce ^ cf, E3 = ce & cf;

        u64 n0, n1, n2, n3, Fv;
        if (j == 0) {
            u64 m = (col0 == 0) ? ~0ull : 0ull;
            n0 = (B0 & m) | (A0 & ~m); n1 = (B1 & m) | (A1 & ~m);
            n2 = (B2 & m) | (A2 & ~m); n3 = (B3 & m) | (A3 & ~m);
            Fv = (B4 & m) | (A4 & ~m);
        } else if (j == 3) {
            u64 m = (col0 == 52) ? ~0ull : 0ull;
            n0 = (B0 & m) | (A0 & ~m); n1 = (B1 & m) | (A1 & ~m);
            n2 = (B2 & m) | (A2 & ~m); n3 = (B3 & m) | (A3 & ~m);
            Fv = (B4 & m) | (A4 & ~m);
        } else {
            n0 = A0; n1 = A1; n2 = A2; n3 = A3; Fv = A4;
        }

        // carry-out of E + ~T* + 1  ->  (E >= T*)
        u64 c = E0 | n0;
        c = (E1 & n1) | (c & (E1 | n1));
        c = (E2 & n2) | (c & (E2 | n2));
        c = (E3 & n3) | (c & (E3 | n3));
        out[j] = c ^ Fv;
    }

    u64* sp = s1 + (size_t)cw * NPOS + (size_t)b * HW + r * WW + col0;
    *(ulonglong2*)(sp)     = make_ulonglong2(out[0], out[1]);
    *(ulonglong2*)(sp + 2) = make_ulonglong2(out[2], out[3]);
}

// K2: 1x1 binary conv via XNOR-popcount + BN2.
// Wide-store remap: lane owns 4 consecutive positions, wave owns a 32-output
// slice -> every wave store is a 1KB contiguous float4 burst (R16 mechanism
// applied to writes); grid/block/TLP identical to the 133us champion.
// grid (392, 4) x 256
__global__ __launch_bounds__(256) void pw_kernel(
    const u64* __restrict__ s1, const u64* __restrict__ wbits,
    const float* __restrict__ bn2inv, const float* __restrict__ bn2beta,
    float* __restrict__ out) {
    __shared__ u64  wb[128 * 8];
    __shared__ float inv_s[128], beta_s[128];
    const int tid = threadIdx.x;
    const int o0  = blockIdx.y * 128;

    for (int i = tid; i < 1024; i += 256) wb[i] = wbits[(size_t)o0 * 8 + i];
    if (tid < 128) { inv_s[tid] = bn2inv[o0 + tid]; beta_s[tid] = bn2beta[o0 + tid]; }
    __syncthreads();

    const int lane = tid & 63;
    const int wv   = tid >> 6;                      // wave 0..3 -> 32-output slice
    const size_t p = (size_t)blockIdx.x * 256 + (size_t)lane * 4;  // 4 consecutive positions
    const int    b   = (int)(p / HW);               // 3136%4==0 -> no batch straddle
    const int    idx = (int)(p - (size_t)b * HW);

    // load 4 positions x 8 words (1KB contiguous per wave-load instruction)
    u64 r0[4], r1[4], r2[4], r3[4], r4[4], r5[4], r6[4], r7[4];
    #pragma unroll
    for (int h = 0; h < 1; ++h) {}  // (keep structure flat)
    {
        const u64* sp;
        u64x2 qa, qb;
        sp = s1 + 0u * NPOS + p; qa = __builtin_nontemporal_load((const u64x2*)sp); qb = __builtin_nontemporal_load((const u64x2*)(sp + 2));
        r0[0] = qa.x; r0[1] = qa.y; r0[2] = qb.x; r0[3] = qb.y;
        sp = s1 + 1u * NPOS + p; qa = __builtin_nontemporal_load((const u64x2*)sp); qb = __builtin_nontemporal_load((const u64x2*)(sp + 2));
        r1[0] = qa.x; r1[1] = qa.y; r1[2] = qb.x; r1[3] = qb.y;
        sp = s1 + 2u * NPOS + p; qa = __builtin_nontemporal_load((const u64x2*)sp); qb = __builtin_nontemporal_load((const u64x2*)(sp + 2));
        r2[0] = qa.x; r2[1] = qa.y; r2[2] = qb.x; r2[3] = qb.y;
        sp = s1 + 3u * NPOS + p; qa = __builtin_nontemporal_load((const u64x2*)sp); qb = __builtin_nontemporal_load((const u64x2*)(sp + 2));
        r3[0] = qa.x; r3[1] = qa.y; r3[2] = qb.x; r3[3] = qb.y;
        sp = s1 + 4u * NPOS + p; qa = __builtin_nontemporal_load((const u64x2*)sp); qb = __builtin_nontemporal_load((const u64x2*)(sp + 2));
        r4[0] = qa.x; r4[1] = qa.y; r4[2] = qb.x; r4[3] = qb.y;
        sp = s1 + 5u * NPOS + p; qa = __builtin_nontemporal_load((const u64x2*)sp); qb = __builtin_nontemporal_load((const u64x2*)(sp + 2));
        r5[0] = qa.x; r5[1] = qa.y; r5[2] = qb.x; r5[3] = qb.y;
        sp = s1 + 6u * NPOS + p; qa = __builtin_nontemporal_load((const u64x2*)sp); qb = __builtin_nontemporal_load((const u64x2*)(sp + 2));
        r6[0] = qa.x; r6[1] = qa.y; r6[2] = qb.x; r6[3] = qb.y;
        sp = s1 + 7u * NPOS + p; qa = __builtin_nontemporal_load((const u64x2*)sp); qb = __builtin_nontemporal_load((const u64x2*)(sp + 2));
        r7[0] = qa.x; r7[1] = qa.y; r7[2] = qb.x; r7[3] = qb.y;
    }

    float* outp = out + ((size_t)b * COO) * HW + idx;
    const int olbase = wv * 32;

    #pragma unroll 4
    for (int ol = 0; ol < 32; ++ol) {
        const int o = olbase + ol;
        const u64* w8 = wb + o * 8;
        const u64 q0 = w8[0], q1 = w8[1], q2 = w8[2], q3 = w8[3];
        const u64 q4 = w8[4], q5 = w8[5], q6 = w8[6], q7 = w8[7];
        const float iv = inv_s[o], bt = beta_s[o];
        f32x4 res;
        #pragma unroll
        for (int j = 0; j < 4; ++j) {
            int d = __popcll(r0[j] ^ q0) + __popcll(r1[j] ^ q1)
                  + __popcll(r2[j] ^ q2) + __popcll(r3[j] ^ q3)
                  + __popcll(r4[j] ^ q4) + __popcll(r5[j] ^ q5)
                  + __popcll(r6[j] ^ q6) + __popcll(r7[j] ^ q7);
            res[j] = fmaf((float)(CC - 2 * d), iv, bt);
        }
        __builtin_nontemporal_store(res, (f32x4*)(outp + (size_t)(o0 + o) * HW));
    }
}

extern "C" void kernel_launch(void* const* d_in, const int* in_sizes, int n_in,
                              void* d_out, int out_size, void* d_ws, size_t ws_size,
                              hipStream_t stream) {
    const float* x    = (const float*)d_in[0];
    const float* w_dw = (const float*)d_in[1];
    const float* w_pw = (const float*)d_in[2];
    const float* g1   = (const float*)d_in[3];
    const float* b1   = (const float*)d_in[4];
    const float* m1   = (const float*)d_in[5];
    const float* v1   = (const float*)d_in[6];
    const float* g2   = (const float*)d_in[7];
    const float* b2   = (const float*)d_in[8];
    const float* m2   = (const float*)d_in[9];
    const float* v2   = (const float*)d_in[10];

    char* ws = (char*)d_ws;
    u64*   s1      = (u64*)(ws + OFF_S1);
    u64*   wbits   = (u64*)(ws + OFF_WBITS);
    u64*   wn      = (u64*)(ws + OFF_WN);
    u64*   NTarr   = (u64*)(ws + OFF_NT);
    float* bn2inv  = (float*)(ws + OFF_BN2INV);
    float* bn2beta = (float*)(ws + OFF_BN2BETA);

    setup_kernel<<<16, 256, 0, stream>>>(w_dw, w_pw, g1, b1, m1, v1, g2, b2, m2, v2,
                                         wbits, wn, NTarr, bn2inv, bn2beta);

    dim3 gf(4, 8, BB);
    dwfused_kernel<<<gf, 256, 0, stream>>>(x, wn, NTarr, s1);

    dim3 g2d(392, 4);
    pw_kernel<<<g2d, 256, 0, stream>>>(s1, wbits, bn2inv, bn2beta, (float*)d_out);
}

// Round 18
// 132.260 us; speedup vs baseline: 1.0973x; 1.0973x over previous
//
#include <hip/hip_runtime.h>

#define BB 32
#define CC 512
#define COO 512
#define HH 56
#define WW 56
#define HW 3136
#define NPOS 100352      // B*H*W
#define EPSF 1e-5f
#define TH 28            // output rows per dwfused block
#define LR 30            // staged LDS rows (TH+2)

typedef unsigned long long u64;
typedef unsigned int u32;
typedef unsigned short u16;
typedef float f32x4 __attribute__((ext_vector_type(4)));

// ---------------- workspace layout (bytes) ----------------  total 6,460,928
// s1     : u64[8][NPOS]  = 6,422,528   stage-1 sign bits (word-major)
// wbits  : u64[512*8]    = 32,768      pointwise weight sign bits
// wn     : u64[9*8]      = 576         ~sign(w_dw) per tap per cw
// NT     : u64[3*8*5]    = 960         per-(Nv cat, cw): 4 planes of ~T* + flip
// bn2inv/bn2beta : float[512] each
#define OFF_S1      0
#define OFF_WBITS   6422528
#define OFF_WN      6455296
#define OFF_NT      6455872
#define OFF_BN2INV  6456832
#define OFF_BN2BETA 6458880

__global__ __launch_bounds__(256) void setup_kernel(
    const float* __restrict__ w_dw, const float* __restrict__ w_pw,
    const float* __restrict__ g1, const float* __restrict__ b1,
    const float* __restrict__ m1, const float* __restrict__ v1,
    const float* __restrict__ g2, const float* __restrict__ b2,
    const float* __restrict__ m2, const float* __restrict__ v2,
    u64* __restrict__ wbits, u64* __restrict__ wn, u64* __restrict__ NT,
    float* __restrict__ bn2inv, float* __restrict__ bn2beta) {
    const int t = blockIdx.x * 256 + threadIdx.x;   // 0..4095

    // pointwise weight sign bits (all 4096 threads)
    {
        int o = t >> 3, wi = t & 7;
        const float* wp = w_pw + (size_t)o * CC + wi * 64;
        u64 wrd = 0;
        #pragma unroll 8
        for (int k = 0; k < 64; ++k)
            wrd |= (u64)(wp[k] >= 0.f) << k;
        wbits[t] = wrd;
    }

    if (t < CC) {                       // BN2 affine
        float i2 = g2[t] / sqrtf(v2[t] + EPSF);
        bn2inv[t]  = i2;
        bn2beta[t] = b2[t] - m2[t] * i2;
    } else if (t >= 512 && t < 584) {   // depthwise weight ~sign words
        int q = t - 512, cw = q & 7, tap = q >> 3;   // tap = kh*3+kw
        u64 wv = 0;
        for (int cl = 0; cl < 64; ++cl)
            wv |= (u64)(w_dw[(size_t)(cw * 64 + cl) * 9 + tap] < 0.f) << cl;
        wn[tap * 8 + cw] = wv;
    } else if (t >= 1024 && t < 1048) { // BN1 threshold bitplanes
        int q = t - 1024, cat = q / 8, cw = q % 8;
        const int Nv = (cat == 0) ? 9 : ((cat == 1) ? 6 : 4);
        u64 p0 = 0, p1 = 0, p2 = 0, p3 = 0, F = 0;
        for (int cl = 0; cl < 64; ++cl) {
            int c = cw * 64 + cl;
            float i1 = g1[c] / sqrtf(v1[c] + EPSF);
            float be = b1[c] - m1[c] * i1;
            int T, f;
            if (i1 > 0.f) {
                double h = ((double)Nv - (double)be / (double)i1) * 0.5;
                f = 0;
                if (!(h > 0.0)) T = 0;
                else if (h > 15.0) T = 15;
                else T = (int)ceil(h);
            } else if (i1 < 0.f) {
                double h = ((double)Nv - (double)be / (double)i1) * 0.5;
                f = 1;
                if (h < 0.0) T = 0;
                else if (h >= 15.0) T = 15;
                else { T = (int)floor(h) + 1; if (T > 15) T = 15; }
            } else {
                f = 0;
                T = (be >= 0.f) ? 0 : 15;   // always true / never true (E<=9<15)
            }
            unsigned nt = (~(unsigned)T) & 0xFu;
            p0 |= (u64)(nt & 1) << cl;
            p1 |= (u64)((nt >> 1) & 1) << cl;
            p2 |= (u64)((nt >> 2) & 1) << cl;
            p3 |= (u64)((nt >> 3) & 1) << cl;
            F  |= (u64)f << cl;
        }
        u64* d = NT + (size_t)(cat * 8 + cw) * 5;
        d[0] = p0; d[1] = p1; d[2] = p2; d[3] = p3; d[4] = F;
    }
}

__device__ __forceinline__ void fa(u64 a, u64 b, u64 c, u64& s, u64& cy) {
    u64 ab = a ^ b;
    s  = ab ^ c;
    cy = (ab & c) | (a & b);
}

// Fused: binarize(x) -> LDS bitpack -> depthwise 3x3 + BN1 + sign (bit-domain) -> s1
// TH=28: halo ratio 30/28 (vs 16/14) -> 6% fewer staged bytes.
// grid (strip=2, cw=8, b=32) x 256; contiguous pack order + NT loads (R16 mechanism).
__global__ __launch_bounds__(256, 4) void dwfused_kernel(
    const float* __restrict__ x, const u64* __restrict__ wn,
    const u64* __restrict__ NT, u64* __restrict__ s1) {
    __shared__ u64 xb[LR * 56];          // rows r0-1 .. r0+TH, 13,440 B
    const int strip = blockIdx.x;
    const int cw    = blockIdx.y;
    const int b     = blockIdx.z;
    const int tid   = threadIdx.x;
    const int r0    = strip * TH;

    const float* xc = x + ((size_t)b * CC + cw * 64) * HW;
    u16* xb16 = (u16*)xb;

    // ---- pack phase: 1680 tasks = 4 ch-slices x 30 lds-rows x 14 colgroups
    // (cg, lrow, colgrp) order: lanes sweep colgrp then lrow => contiguous
    // plane bytes per wave-load instruction.
    for (int tau = tid; tau < 4 * LR * 14; tau += 256) {
        const int cg     = tau / (LR * 14);
        const int rem    = tau - cg * (LR * 14);
        const int lrow   = rem / 14;
        const int colgrp = rem - lrow * 14;
        const int h      = r0 - 1 + lrow;
        const int col0   = colgrp * 4;
        u16 o0 = 0, o1 = 0, o2 = 0, o3 = 0;
        if (h >= 0 && h < HH) {
            const float* bp = xc + (size_t)(cg * 16) * HW + h * WW + col0;
            f32x4 vv[16];
            #pragma unroll
            for (int cl = 0; cl < 16; ++cl)
                vv[cl] = __builtin_nontemporal_load((const f32x4*)(bp + (size_t)cl * HW));
            u32 a0 = 0, a1 = 0, a2 = 0, a3 = 0;
            #pragma unroll
            for (int cl = 0; cl < 16; ++cl) {
                a0 |= (__float_as_uint(vv[cl].x) >> 31) << cl;
                a1 |= (__float_as_uint(vv[cl].y) >> 31) << cl;
                a2 |= (__float_as_uint(vv[cl].z) >> 31) << cl;
                a3 |= (__float_as_uint(vv[cl].w) >> 31) << cl;
            }
            o0 = (u16)(~a0); o1 = (u16)(~a1); o2 = (u16)(~a2); o3 = (u16)(~a3);
        }
        const int wbase = lrow * 56 + col0;
        xb16[(wbase + 0) * 4 + cg] = o0;
        xb16[(wbase + 1) * 4 + cg] = o1;
        xb16[(wbase + 2) * 4 + cg] = o2;
        xb16[(wbase + 3) * 4 + cg] = o3;
    }
    __syncthreads();

    // ---- compute phase: 392 tasks (28 rows x 14 colgroups) x 4 words each
    for (int task = tid; task < TH * 14; task += 256) {
        const int q      = task / 14;         // row within strip
        const int colgrp = task - q * 14;
        const int col0   = colgrp * 4;
        const int r      = r0 + q;            // global row
        const int lrow   = q + 1;

        const int c_m1 = (col0 == 0)  ? 0  : col0 - 1;
        const int c_p4 = (col0 == 52) ? 55 : col0 + 4;

        const u64* rowT = xb + (lrow - 1) * 56;
        const u64* rowM = xb + lrow * 56;
        const u64* rowB = xb + (lrow + 1) * 56;

        u64 rT[6], rM[6], rB[6];
        rT[0] = rowT[c_m1]; rT[1] = rowT[col0];   rT[2] = rowT[col0+1];
        rT[3] = rowT[col0+2]; rT[4] = rowT[col0+3]; rT[5] = rowT[c_p4];
        rM[0] = rowM[c_m1]; rM[1] = rowM[col0];   rM[2] = rowM[col0+1];
        rM[3] = rowM[col0+2]; rM[4] = rowM[col0+3]; rM[5] = rowM[c_p4];
        rB[0] = rowB[c_m1]; rB[1] = rowB[col0];   rB[2] = rowB[col0+1];
        rB[3] = rowB[col0+2]; rB[4] = rowB[col0+3]; rB[5] = rowB[c_p4];

        const u64 w00 = wn[0*8+cw], w01 = wn[1*8+cw], w02 = wn[2*8+cw];
        const u64 w10 = wn[3*8+cw], w11 = wn[4*8+cw], w12 = wn[5*8+cw];
        const u64 w20 = wn[6*8+cw], w21 = wn[7*8+cw], w22 = wn[8*8+cw];

        const u64 mt = (r > 0)    ? ~0ull : 0ull;
        const u64 mb = (r < 55)   ? ~0ull : 0ull;
        const u64 mL = (col0 > 0) ? ~0ull : 0ull;
        const u64 mR = (col0 < 52)? ~0ull : 0ull;

        const bool rowe = (r == 0) || (r == 55);
        const u64* NTc = NT + (size_t)cw * 5;   // cat stride = 40 u64
        u64 A0 = rowe ? NTc[40+0] : NTc[0];
        u64 A1 = rowe ? NTc[40+1] : NTc[1];
        u64 A2 = rowe ? NTc[40+2] : NTc[2];
        u64 A3 = rowe ? NTc[40+3] : NTc[3];
        u64 A4 = rowe ? NTc[40+4] : NTc[4];
        u64 B0 = rowe ? NTc[80+0] : NTc[40+0];
        u64 B1 = rowe ? NTc[80+1] : NTc[40+1];
        u64 B2 = rowe ? NTc[80+2] : NTc[40+2];
        u64 B3 = rowe ? NTc[80+3] : NTc[40+3];
        u64 B4 = rowe ? NTc[80+4] : NTc[40+4];

        u64 out[4];
        #pragma unroll
        for (int j = 0; j < 4; ++j) {
            u64 e0 = (rT[j]   ^ w00) & mt;
            u64 e1 = (rT[j+1] ^ w01) & mt;
            u64 e2 = (rT[j+2] ^ w02) & mt;
            u64 e3 = (rM[j]   ^ w10);
            u64 e4 = (rM[j+1] ^ w11);
            u64 e5 = (rM[j+2] ^ w12);
            u64 e6 = (rB[j]   ^ w20) & mb;
            u64 e7 = (rB[j+1] ^ w21) & mb;
            u64 e8 = (rB[j+2] ^ w22) & mb;
            if (j == 0) { e0 &= mL; e3 &= mL; e6 &= mL; }
            if (j == 3) { e2 &= mR; e5 &= mR; e8 &= mR; }

            u64 sa, ca, sb, cb, sc, cc, E0, cd, se, ce;
            fa(e0, e1, e2, sa, ca);
            fa(e3, e4, e5, sb, cb);
            fa(e6, e7, e8, sc, cc);
            fa(sa, sb, sc, E0, cd);
            fa(ca, cb, cc, se, ce);
            u64 E1 = se ^ cd, cf = se & cd;
            u64 E2 = ce ^ cf, E3 = ce & cf;

            u64 n0, n1, n2, n3, Fv;
            if (j == 0) {
                u64 m = (col0 == 0) ? ~0ull : 0ull;
                n0 = (B0 & m) | (A0 & ~m); n1 = (B1 & m) | (A1 & ~m);
                n2 = (B2 & m) | (A2 & ~m); n3 = (B3 & m) | (A3 & ~m);
                Fv = (B4 & m) | (A4 & ~m);
            } else if (j == 3) {
                u64 m = (col0 == 52) ? ~0ull : 0ull;
                n0 = (B0 & m) | (A0 & ~m); n1 = (B1 & m) | (A1 & ~m);
                n2 = (B2 & m) | (A2 & ~m); n3 = (B3 & m) | (A3 & ~m);
                Fv = (B4 & m) | (A4 & ~m);
            } else {
                n0 = A0; n1 = A1; n2 = A2; n3 = A3; Fv = A4;
            }

            // carry-out of E + ~T* + 1  ->  (E >= T*)
            u64 c = E0 | n0;
            c = (E1 & n1) | (c & (E1 | n1));
            c = (E2 & n2) | (c & (E2 | n2));
            c = (E3 & n3) | (c & (E3 | n3));
            out[j] = c ^ Fv;
        }

        u64* sp = s1 + (size_t)cw * NPOS + (size_t)b * HW + r * WW + col0;
        *(ulonglong2*)(sp)     = make_ulonglong2(out[0], out[1]);
        *(ulonglong2*)(sp + 2) = make_ulonglong2(out[2], out[3]);
    }
}

// K2: 1x1 binary conv via XNOR-popcount + BN2 (byte-identical to 133us champion)
// NT loads for s1, NT stores for out. grid (392, 4) x 256
__global__ __launch_bounds__(256) void pw_kernel(
    const u64* __restrict__ s1, const u64* __restrict__ wbits,
    const float* __restrict__ bn2inv, const float* __restrict__ bn2beta,
    float* __restrict__ out) {
    __shared__ u64  wb[128 * 8];
    __shared__ float inv_s[128], beta_s[128];
    const int tid = threadIdx.x;
    const int o0  = blockIdx.y * 128;

    for (int i = tid; i < 1024; i += 256) wb[i] = wbits[(size_t)o0 * 8 + i];
    if (tid < 128) { inv_s[tid] = bn2inv[o0 + tid]; beta_s[tid] = bn2beta[o0 + tid]; }
    __syncthreads();

    const size_t p   = (size_t)blockIdx.x * 256 + tid;
    const int    b   = (int)(p / HW);
    const int    idx = (int)(p - (size_t)b * HW);

    u64 r0 = __builtin_nontemporal_load(s1 + 0u * NPOS + p);
    u64 r1 = __builtin_nontemporal_load(s1 + 1u * NPOS + p);
    u64 r2 = __builtin_nontemporal_load(s1 + 2u * NPOS + p);
    u64 r3 = __builtin_nontemporal_load(s1 + 3u * NPOS + p);
    u64 r4 = __builtin_nontemporal_load(s1 + 4u * NPOS + p);
    u64 r5 = __builtin_nontemporal_load(s1 + 5u * NPOS + p);
    u64 r6 = __builtin_nontemporal_load(s1 + 6u * NPOS + p);
    u64 r7 = __builtin_nontemporal_load(s1 + 7u * NPOS + p);

    float* outp = out + ((size_t)b * COO) * HW + idx;

    for (int ol = 0; ol < 128; ++ol) {
        const u64* w8 = wb + ol * 8;
        int d = __popcll(r0 ^ w8[0]) + __popcll(r1 ^ w8[1])
              + __popcll(r2 ^ w8[2]) + __popcll(r3 ^ w8[3])
              + __popcll(r4 ^ w8[4]) + __popcll(r5 ^ w8[5])
              + __popcll(r6 ^ w8[6]) + __popcll(r7 ^ w8[7]);
        float res = (float)(CC - 2 * d);
        __builtin_nontemporal_store(fmaf(res, inv_s[ol], beta_s[ol]),
                                    outp + (size_t)(o0 + ol) * HW);
    }
}

extern "C" void kernel_launch(void* const* d_in, const int* in_sizes, int n_in,
                              void* d_out, int out_size, void* d_ws, size_t ws_size,
                              hipStream_t stream) {
    const float* x    = (const float*)d_in[0];
    const float* w_dw = (const float*)d_in[1];
    const float* w_pw = (const float*)d_in[2];
    const float* g1   = (const float*)d_in[3];
    const float* b1   = (const float*)d_in[4];
    const float* m1   = (const float*)d_in[5];
    const float* v1   = (const float*)d_in[6];
    const float* g2   = (const float*)d_in[7];
    const float* b2   = (const float*)d_in[8];
    const float* m2   = (const float*)d_in[9];
    const float* v2   = (const float*)d_in[10];

    char* ws = (char*)d_ws;
    u64*   s1      = (u64*)(ws + OFF_S1);
    u64*   wbits   = (u64*)(ws + OFF_WBITS);
    u64*   wn      = (u64*)(ws + OFF_WN);
    u64*   NTarr   = (u64*)(ws + OFF_NT);
    float* bn2inv  = (float*)(ws + OFF_BN2INV);
    float* bn2beta = (float*)(ws + OFF_BN2BETA);

    setup_kernel<<<16, 256, 0, stream>>>(w_dw, w_pw, g1, b1, m1, v1, g2, b2, m2, v2,
                                         wbits, wn, NTarr, bn2inv, bn2beta);

    dim3 gf(2, 8, BB);
    dwfused_kernel<<<gf, 256, 0, stream>>>(x, wn, NTarr, s1);

    dim3 g2d(392, 4);
    pw_kernel<<<g2d, 256, 0, stream>>>(s1, wbits, bn2inv, bn2beta, (float*)d_out);
}